// Round 2
// baseline (801.877 us; speedup 1.0000x reference)
//
#include <hip/hip_runtime.h>

// Problem dims
#define B_    8
#define N_    1024
#define DIN   512
#define H_    8
#define DH    64
#define DQKV  6144   // 2*DQ + 2*DQ + DV = 512+512+512+512+4096
#define DEXP  2048
#define DTIME 256

typedef __attribute__((ext_vector_type(8))) short s16x8;   // 8 bf16 (MFMA A/B frag)
typedef __attribute__((ext_vector_type(4))) short s16x4;
typedef __attribute__((ext_vector_type(4))) float f32x4;   // MFMA C/D frag

__device__ __forceinline__ unsigned short f2bf(float f) {
  unsigned int u = __float_as_uint(f);
  u = (u + 0x7fffu + ((u >> 16) & 1u)) >> 16;   // RNE
  return (unsigned short)u;
}

__device__ __forceinline__ void gload_lds16(const unsigned short* g, unsigned short* l) {
  __builtin_amdgcn_global_load_lds(
      (const __attribute__((address_space(1))) unsigned int*)(g),
      (__attribute__((address_space(3))) unsigned int*)(l), 16, 0, 0);
}

// ---------------- LayerNorm (D=512), optional per-batch additive row, bf16 out ----
__global__ __launch_bounds__(256) void ln_k(
    const float* __restrict__ x, const float* __restrict__ add,
    const float* __restrict__ g, const float* __restrict__ bb,
    unsigned short* __restrict__ out)
{
  int row = blockIdx.x;
  int tid = threadIdx.x;
  const float* xr = x + (size_t)row * DIN;
  float v0 = xr[tid], v1 = xr[tid + 256];
  if (add) {
    const float* ar = add + (size_t)(row >> 10) * DIN;   // row/1024 = batch idx
    v0 += ar[tid]; v1 += ar[tid + 256];
  }
  float s = v0 + v1, sq = v0 * v0 + v1 * v1;
  #pragma unroll
  for (int m = 1; m < 64; m <<= 1) { s += __shfl_xor(s, m, 64); sq += __shfl_xor(sq, m, 64); }
  __shared__ float red[8];
  int w = tid >> 6;
  if ((tid & 63) == 0) { red[w] = s; red[4 + w] = sq; }
  __syncthreads();
  s  = red[0] + red[1] + red[2] + red[3];
  sq = red[4] + red[5] + red[6] + red[7];
  float mean = s * (1.0f / DIN);
  float var  = sq * (1.0f / DIN) - mean * mean;
  float rs = rsqrtf(var + 1e-5f);
  unsigned short* orow = out + (size_t)row * DIN;
  orow[tid]       = f2bf((v0 - mean) * rs * g[tid]       + bb[tid]);
  orow[tid + 256] = f2bf((v1 - mean) * rs * g[tid + 256] + bb[tid + 256]);
}

// ---------------- f32 [R][C] -> bf16 [C][R] transpose (weights) ------------------
__global__ __launch_bounds__(256) void wtrans_k(
    const float* __restrict__ in, unsigned short* __restrict__ out, int R, int C)
{
  __shared__ float tile[32][33];
  int tx = threadIdx.x & 31, ty = threadIdx.x >> 5;
  int c0 = blockIdx.x * 32, r0 = blockIdx.y * 32;
  #pragma unroll
  for (int k = 0; k < 4; ++k)
    tile[ty + k * 8][tx] = in[(size_t)(r0 + ty + k * 8) * C + c0 + tx];
  __syncthreads();
  #pragma unroll
  for (int k = 0; k < 4; ++k)
    out[(size_t)(c0 + ty + k * 8) * R + r0 + tx] = f2bf(tile[tx][ty + k * 8]);
}

// ---------------- time MLP: tp[b][512] = swish(t@Wt1+bt1)@Wt2+bt2 ---------------
__global__ __launch_bounds__(256) void time_k(
    const float* __restrict__ t, const float* __restrict__ Wt1, const float* __restrict__ bt1,
    const float* __restrict__ Wt2, const float* __restrict__ bt2, float* __restrict__ tp)
{
  int b = blockIdx.x, tid = threadIdx.x;
  __shared__ float tl[256], hl[256];
  tl[tid] = t[(size_t)b * 256 + tid];
  __syncthreads();
  float a = bt1[tid];
  for (int k = 0; k < 256; ++k) a += tl[k] * Wt1[(size_t)k * 256 + tid];
  hl[tid] = a / (1.0f + __expf(-a));
  __syncthreads();
  for (int j = tid; j < 512; j += 256) {
    float a2 = bt2[j];
    for (int k = 0; k < 256; ++k) a2 += hl[k] * Wt2[(size_t)k * 512 + j];
    tp[(size_t)b * 512 + j] = a2;
  }
}

// ---------------- bf16 MFMA GEMM: C = epi(A @ Bt^T + bias [+res]) ---------------
// A [M][lda] bf16 ; Bt [N][K] bf16 ; 128x128 tile, BK=32, 4 waves (2x2 of 64x64)
// global_load_lds width-16 staging into linear LDS (m97 structure).
// EPI: 0 = bias -> bf16 ; 1 = bias+swish -> bf16 ; 2 = bias+res(f32) -> f32
//      3 = bias -> bf16, but V-columns (n0>=2048) written transposed into vtout
template<int EPI>
__global__ __launch_bounds__(256) void gemm_bt(
    const unsigned short* __restrict__ A, int lda,
    const unsigned short* __restrict__ Bt,
    const float* __restrict__ bias, const float* __restrict__ res,
    void* __restrict__ C, int ldc, int N, int K,
    unsigned short* __restrict__ vtout)
{
  __shared__ __attribute__((aligned(16))) unsigned short As[128 * 32];
  __shared__ __attribute__((aligned(16))) unsigned short Bs[128 * 32];
  int tid = threadIdx.x;
  int m0 = blockIdx.y * 128, n0 = blockIdx.x * 128;
  int lane = tid & 63, wid = tid >> 6;
  int wr = wid >> 1, wc = wid & 1;
  int lr = lane & 15, lg = lane >> 4, lk = lg * 8;
  f32x4 zero = {0.f, 0.f, 0.f, 0.f};
  f32x4 acc[4][4];
  #pragma unroll
  for (int i = 0; i < 4; ++i)
    #pragma unroll
    for (int j = 0; j < 4; ++j) acc[i][j] = zero;
  // staging: wave wid covers rows wid*16..wid*16+15 of each 64-row half
  int srow = wid * 16 + (lane >> 2);
  int schunk = (lane & 3) * 8;
  const unsigned short* gA0 = A  + (size_t)(m0 + srow) * lda + schunk;
  const unsigned short* gA1 = gA0 + (size_t)64 * lda;
  const unsigned short* gB0 = Bt + (size_t)(n0 + srow) * K + schunk;
  const unsigned short* gB1 = gB0 + (size_t)64 * K;
  unsigned short* lA0 = As + wid * 512;          // wave-uniform bases
  unsigned short* lA1 = As + 2048 + wid * 512;
  unsigned short* lB0 = Bs + wid * 512;
  unsigned short* lB1 = Bs + 2048 + wid * 512;
  for (int kt = 0; kt < K; kt += 32) {
    gload_lds16(gA0 + kt, lA0);
    gload_lds16(gA1 + kt, lA1);
    gload_lds16(gB0 + kt, lB0);
    gload_lds16(gB1 + kt, lB1);
    __syncthreads();
    s16x8 af[4], bf[4];
    #pragma unroll
    for (int mf = 0; mf < 4; ++mf) af[mf] = *(const s16x8*)&As[(wr * 64 + mf * 16 + lr) * 32 + lk];
    #pragma unroll
    for (int nf = 0; nf < 4; ++nf) bf[nf] = *(const s16x8*)&Bs[(wc * 64 + nf * 16 + lr) * 32 + lk];
    #pragma unroll
    for (int mf = 0; mf < 4; ++mf)
      #pragma unroll
      for (int nf = 0; nf < 4; ++nf)
        acc[mf][nf] = __builtin_amdgcn_mfma_f32_16x16x32_bf16(af[mf], bf[nf], acc[mf][nf], 0, 0, 0);
    __syncthreads();
  }
  if (EPI == 3 && n0 >= 2048) {
    // V columns -> vt [bh][c(512)][kv(1024)], packed 8B stores (4 consecutive kv)
    #pragma unroll
    for (int mf = 0; mf < 4; ++mf) {
      int row = m0 + wr * 64 + mf * 16 + lg * 4;
      int bb = row >> 10, nn = row & 1023;
      #pragma unroll
      for (int nf = 0; nf < 4; ++nf) {
        int col = n0 + wc * 64 + nf * 16 + lr;
        float bcol = bias[col];
        int hc = col - 2048;
        int hh = hc >> 9, cc = hc & 511;
        unsigned short pk[4];
        #pragma unroll
        for (int r = 0; r < 4; ++r) pk[r] = f2bf(acc[mf][nf][r] + bcol);
        *(s16x4*)(vtout + ((size_t)((bb * 8 + hh) * 512 + cc)) * 1024 + nn) = *(const s16x4*)pk;
      }
    }
    return;
  }
  #pragma unroll
  for (int mf = 0; mf < 4; ++mf)
    #pragma unroll
    for (int nf = 0; nf < 4; ++nf) {
      int col = n0 + wc * 64 + nf * 16 + lr;
      float bcol = bias[col];
      #pragma unroll
      for (int r = 0; r < 4; ++r) {
        int row = m0 + wr * 64 + mf * 16 + lg * 4 + r;
        float v = acc[mf][nf][r] + bcol;
        if (EPI == 1) v = v / (1.0f + __expf(-v));            // swish
        if (EPI == 2) {
          v += res[(size_t)row * N + col];
          ((float*)C)[(size_t)row * ldc + col] = v;
        } else {
          ((unsigned short*)C)[(size_t)row * ldc + col] = f2bf(v);
        }
      }
    }
}

// ---------------- attention pass A: exact row stats (m,l) for both softmaxes ----
// block = (b,h,qtile of 64 rows), 4 waves; wave w owns rows w*16..w*16+15
// Per-lane online m/l in the k-loop; single 16-lane merge at the end.
__global__ __launch_bounds__(256) void attn_stats_k(
    const unsigned short* __restrict__ qkv,
    float* __restrict__ stm1, float* __restrict__ stl1,
    float* __restrict__ stm2, float* __restrict__ stl2)
{
  const float scale = 0.125f;
  int bx = blockIdx.x;
  int bh = bx >> 4, qt = bx & 15;
  int b = bh >> 3, h = bh & 7;
  int tid = threadIdx.x;
  int lane = tid & 63, w = tid >> 6;
  int lr = lane & 15, lg = lane >> 4, lk = lg * 8;
  size_t qrowoff = (size_t)(b * N_ + qt * 64 + w * 16 + lr) * DQKV;
  int qc1 = h * 64, qc2 = 512 + h * 64, kc1 = 1024 + h * 64, kc2 = 1536 + h * 64;
  s16x8 q1f[2], q2f[2];
  #pragma unroll
  for (int kf = 0; kf < 2; ++kf) {
    q1f[kf] = *(const s16x8*)(qkv + qrowoff + qc1 + kf * 32 + lk);
    q2f[kf] = *(const s16x8*)(qkv + qrowoff + qc2 + kf * 32 + lk);
  }
  float m1p[4], l1p[4], m2p[4], l2p[4];
  #pragma unroll
  for (int r = 0; r < 4; ++r) { m1p[r] = -1e30f; l1p[r] = 0.f; m2p[r] = -1e30f; l2p[r] = 0.f; }
  f32x4 zero = {0.f, 0.f, 0.f, 0.f};
  for (int kt = 0; kt < 16; ++kt) {
    f32x4 s1[4], s2[4];
    #pragma unroll
    for (int nf = 0; nf < 4; ++nf) {
      s1[nf] = zero; s2[nf] = zero;
      size_t krowoff = (size_t)(b * N_ + kt * 64 + nf * 16 + lr) * DQKV;
      #pragma unroll
      for (int kf = 0; kf < 2; ++kf) {
        s16x8 k1f = *(const s16x8*)(qkv + krowoff + kc1 + kf * 32 + lk);
        s16x8 k2f = *(const s16x8*)(qkv + krowoff + kc2 + kf * 32 + lk);
        s1[nf] = __builtin_amdgcn_mfma_f32_16x16x32_bf16(q1f[kf], k1f, s1[nf], 0, 0, 0);
        s2[nf] = __builtin_amdgcn_mfma_f32_16x16x32_bf16(q2f[kf], k2f, s2[nf], 0, 0, 0);
      }
    }
    #pragma unroll
    for (int r = 0; r < 4; ++r) {
      {
        float v0 = s1[0][r] * scale, v1 = s1[1][r] * scale, v2 = s1[2][r] * scale, v3 = s1[3][r] * scale;
        float nm = fmaxf(m1p[r], fmaxf(fmaxf(v0, v1), fmaxf(v2, v3)));
        l1p[r] = l1p[r] * __expf(m1p[r] - nm)
               + __expf(v0 - nm) + __expf(v1 - nm) + __expf(v2 - nm) + __expf(v3 - nm);
        m1p[r] = nm;
      }
      {
        float v0 = s2[0][r] * scale, v1 = s2[1][r] * scale, v2 = s2[2][r] * scale, v3 = s2[3][r] * scale;
        float nm = fmaxf(m2p[r], fmaxf(fmaxf(v0, v1), fmaxf(v2, v3)));
        l2p[r] = l2p[r] * __expf(m2p[r] - nm)
               + __expf(v0 - nm) + __expf(v1 - nm) + __expf(v2 - nm) + __expf(v3 - nm);
        m2p[r] = nm;
      }
    }
  }
  #pragma unroll
  for (int r = 0; r < 4; ++r) {
    #pragma unroll
    for (int m = 1; m < 16; m <<= 1) {
      float om = __shfl_xor(m1p[r], m, 64), ol = __shfl_xor(l1p[r], m, 64);
      float nm = fmaxf(m1p[r], om);
      l1p[r] = l1p[r] * __expf(m1p[r] - nm) + ol * __expf(om - nm);
      m1p[r] = nm;
      om = __shfl_xor(m2p[r], m, 64); ol = __shfl_xor(l2p[r], m, 64);
      nm = fmaxf(m2p[r], om);
      l2p[r] = l2p[r] * __expf(m2p[r] - nm) + ol * __expf(om - nm);
      m2p[r] = nm;
    }
  }
  if (lr == 0) {
    #pragma unroll
    for (int r = 0; r < 4; ++r) {
      int idx = bh * N_ + qt * 64 + w * 16 + lg * 4 + r;
      stm1[idx] = m1p[r]; stl1[idx] = l1p[r]; stm2[idx] = m2p[r]; stl2[idx] = l2p[r];
    }
  }
}

// ---------------- attention pass B: P = e1/l1 - lam*e2/l2 ; O = P @ V -----------
// block = (b,h,qtile of 32 rows), 8 waves. Per 128-kv iteration: wave w computes
// S1 AND S2 for kv-chunk w*16 (in-register P via preloaded stats), writes bf16 P
// to double-buffered LDS, ONE barrier, then PV for its v-cols [w*64, w*64+64).
__global__ __launch_bounds__(512) void attn_pv_k(
    const unsigned short* __restrict__ qkv, const unsigned short* __restrict__ vt,
    const float* __restrict__ stm1, const float* __restrict__ stl1,
    const float* __restrict__ stm2, const float* __restrict__ stl2,
    const float* __restrict__ lamp, unsigned short* __restrict__ aout /* = qkv+2048 */)
{
  const float scale = 0.125f;
  __shared__ __attribute__((aligned(16))) unsigned short P[2][32][136]; // pad 8 -> 2-way free
  int bx = blockIdx.x;
  int bh = bx >> 5, qt = bx & 31;
  int b = bh >> 3, h = bh & 7;
  int tid = threadIdx.x;
  int lane = tid & 63, w = tid >> 6;
  int lr = lane & 15, lg = lane >> 4, lk = lg * 8;
  float lam = *lamp;
  // stats for the 8 q-rows this lane's acc registers map to (q = mf*16+lg*4+r)
  float m1v[2][4], r1v[2][4], m2v[2][4], r2v[2][4];
  #pragma unroll
  for (int mf = 0; mf < 2; ++mf)
    #pragma unroll
    for (int r = 0; r < 4; ++r) {
      int qg = bh * N_ + qt * 32 + mf * 16 + lg * 4 + r;
      m1v[mf][r] = stm1[qg]; r1v[mf][r] = 1.f / stl1[qg];
      m2v[mf][r] = stm2[qg]; r2v[mf][r] = lam / stl2[qg];
    }
  int qc1 = h * 64, qc2 = 512 + h * 64, kc1 = 1024 + h * 64, kc2 = 1536 + h * 64;
  s16x8 q1f[2][2], q2f[2][2];
  #pragma unroll
  for (int mf = 0; mf < 2; ++mf)
    #pragma unroll
    for (int kf = 0; kf < 2; ++kf) {
      size_t ro = (size_t)(b * N_ + qt * 32 + mf * 16 + lr) * DQKV;
      q1f[mf][kf] = *(const s16x8*)(qkv + ro + qc1 + kf * 32 + lk);
      q2f[mf][kf] = *(const s16x8*)(qkv + ro + qc2 + kf * 32 + lk);
    }
  f32x4 zero = {0.f, 0.f, 0.f, 0.f};
  f32x4 O[2][4];
  #pragma unroll
  for (int mf = 0; mf < 2; ++mf)
    #pragma unroll
    for (int nf = 0; nf < 4; ++nf) O[mf][nf] = zero;
  for (int it = 0; it < 8; ++it) {
    f32x4 s1a[2], s2a[2];
    s1a[0] = zero; s1a[1] = zero; s2a[0] = zero; s2a[1] = zero;
    size_t kro = (size_t)(b * N_ + it * 128 + w * 16 + lr) * DQKV;
    #pragma unroll
    for (int kf = 0; kf < 2; ++kf) {
      s16x8 k1 = *(const s16x8*)(qkv + kro + kc1 + kf * 32 + lk);
      s16x8 k2 = *(const s16x8*)(qkv + kro + kc2 + kf * 32 + lk);
      #pragma unroll
      for (int mf = 0; mf < 2; ++mf) {
        s1a[mf] = __builtin_amdgcn_mfma_f32_16x16x32_bf16(q1f[mf][kf], k1, s1a[mf], 0, 0, 0);
        s2a[mf] = __builtin_amdgcn_mfma_f32_16x16x32_bf16(q2f[mf][kf], k2, s2a[mf], 0, 0, 0);
      }
    }
    int pb = it & 1;
    #pragma unroll
    for (int mf = 0; mf < 2; ++mf)
      #pragma unroll
      for (int r = 0; r < 4; ++r) {
        float p = __expf(s1a[mf][r] * scale - m1v[mf][r]) * r1v[mf][r]
                - __expf(s2a[mf][r] * scale - m2v[mf][r]) * r2v[mf][r];
        P[pb][mf * 16 + lg * 4 + r][w * 16 + lr] = f2bf(p);
      }
    __syncthreads();
    #pragma unroll
    for (int kf = 0; kf < 4; ++kf) {
      s16x8 pf0 = *(const s16x8*)&P[pb][lr][kf * 32 + lk];
      s16x8 pf1 = *(const s16x8*)&P[pb][16 + lr][kf * 32 + lk];
      #pragma unroll
      for (int nf = 0; nf < 4; ++nf) {
        s16x8 vf = *(const s16x8*)(vt + (size_t)(bh * 512 + w * 64 + nf * 16 + lr) * N_
                                   + it * 128 + kf * 32 + lk);
        O[0][nf] = __builtin_amdgcn_mfma_f32_16x16x32_bf16(pf0, vf, O[0][nf], 0, 0, 0);
        O[1][nf] = __builtin_amdgcn_mfma_f32_16x16x32_bf16(pf1, vf, O[1][nf], 0, 0, 0);
      }
    }
  }
  #pragma unroll
  for (int mf = 0; mf < 2; ++mf)
    #pragma unroll
    for (int nf = 0; nf < 4; ++nf) {
      int col = h * 512 + w * 64 + nf * 16 + lr;
      #pragma unroll
      for (int r = 0; r < 4; ++r) {
        int row = b * N_ + qt * 32 + mf * 16 + lg * 4 + r;
        aout[(size_t)row * DQKV + col] = f2bf(O[mf][nf][r]);
      }
    }
}

// ---------------------------------- launcher ------------------------------------
extern "C" void kernel_launch(void* const* d_in, const int* in_sizes, int n_in,
                              void* d_out, int out_size, void* d_ws, size_t ws_size,
                              hipStream_t stream) {
  const float* x    = (const float*)d_in[0];
  const float* t    = (const float*)d_in[1];
  const float* ln1g = (const float*)d_in[2];
  const float* ln1b = (const float*)d_in[3];
  const float* Wqkv = (const float*)d_in[4];
  const float* bqkv = (const float*)d_in[5];
  const float* lam  = (const float*)d_in[6];
  const float* Wm   = (const float*)d_in[7];
  const float* bm   = (const float*)d_in[8];
  const float* Wt1  = (const float*)d_in[9];
  const float* bt1  = (const float*)d_in[10];
  const float* Wt2  = (const float*)d_in[11];
  const float* bt2  = (const float*)d_in[12];
  const float* lnfg = (const float*)d_in[13];
  const float* lnfb = (const float*)d_in[14];
  const float* Wf1  = (const float*)d_in[15];
  const float* bf1  = (const float*)d_in[16];
  const float* Wf2  = (const float*)d_in[17];
  const float* bf2  = (const float*)d_in[18];
  float* out = (float*)d_out;
  char* ws = (char*)d_ws;

  // workspace layout (bytes), ~209 MB total
  unsigned short* qkv   = (unsigned short*)(ws);                  // [8192][6144] bf16 (100.7MB)
  unsigned short* vt    = (unsigned short*)(ws + 100663296ull);   // [64][512][1024] bf16 (67MB)
  float*          x2    = (float*)(ws + 167772160ull);            // [8192][512] f32 (16.8MB)
  unsigned short* xn    = (unsigned short*)(ws + 184549376ull);   // [8192][512] bf16 (xn, then h)
  float*          stm1  = (float*)(ws + 192937984ull);            // 4 x 65536 f32 stats
  float*          stl1  = stm1 + 65536;
  float*          stm2  = stm1 + 131072;
  float*          stl2  = stm1 + 196608;
  unsigned short* WqkvT = (unsigned short*)(ws + 193986560ull);   // [6144][512]
  unsigned short* WmT   = (unsigned short*)(ws + 200278016ull);   // [512][4096]
  unsigned short* Wf1T  = (unsigned short*)(ws + 204472320ull);   // [2048][512]
  unsigned short* Wf2T  = (unsigned short*)(ws + 206569472ull);   // [512][2048]
  float*          tp    = (float*)(ws + 208666624ull);            // [8][512]
  unsigned short* ff1s  = qkv;          // alias: qkv dead after attention
  unsigned short* aout  = qkv + 2048;   // alias: attention out over dead V region

  // weights -> bf16 transposed [N][K]
  wtrans_k<<<dim3(DQKV / 32, DIN / 32),  256, 0, stream>>>(Wqkv, WqkvT, DIN, DQKV);
  wtrans_k<<<dim3(DIN / 32, 4096 / 32),  256, 0, stream>>>(Wm,   WmT,   4096, DIN);
  wtrans_k<<<dim3(DEXP / 32, DIN / 32),  256, 0, stream>>>(Wf1,  Wf1T,  DIN, DEXP);
  wtrans_k<<<dim3(DIN / 32, DEXP / 32),  256, 0, stream>>>(Wf2,  Wf2T,  DEXP, DIN);
  // ln1 + time MLP
  ln_k<<<8192, 256, 0, stream>>>(x, nullptr, ln1g, ln1b, xn);
  time_k<<<8, 256, 0, stream>>>(t, Wt1, bt1, Wt2, bt2, tp);
  // qkv GEMM (V columns written directly transposed into vt)
  gemm_bt<3><<<dim3(DQKV / 128, 8192 / 128), 256, 0, stream>>>(
      xn, DIN, WqkvT, bqkv, nullptr, qkv, DQKV, DQKV, DIN, vt);
  // two-pass differential attention
  attn_stats_k<<<1024, 256, 0, stream>>>(qkv, stm1, stl1, stm2, stl2);
  attn_pv_k<<<2048, 512, 0, stream>>>(qkv, vt, stm1, stl1, stm2, stl2, lam, aout);
  // x2 = x + attn_out @ Wm + bm
  gemm_bt<2><<<dim3(DIN / 128, 8192 / 128), 256, 0, stream>>>(
      aout, DQKV, WmT, bm, x, x2, DIN, DIN, 4096, nullptr);
  // h = LN(x2 + tp)
  ln_k<<<8192, 256, 0, stream>>>(x2, tp, lnfg, lnfb, xn);
  // ff1 = swish(h @ Wf1 + bf1)
  gemm_bt<1><<<dim3(DEXP / 128, 8192 / 128), 256, 0, stream>>>(
      xn, DIN, Wf1T, bf1, nullptr, ff1s, DEXP, DEXP, DIN, nullptr);
  // out = x2 + ff1 @ Wf2 + bf2
  gemm_bt<2><<<dim3(DIN / 128, 8192 / 128), 256, 0, stream>>>(
      ff1s, DEXP, Wf2T, bf2, x2, out, DIN, DIN, DEXP, nullptr);
}